// Round 1
// baseline (243.991 us; speedup 1.0000x reference)
//
#include <hip/hip_runtime.h>
#include <hip/hip_bf16.h>

#define N_ 256
#define C_ 128
#define S_ 961
#define K_ 64
#define TS 64
#define NTILE 16   // ceil(961/64)
#define NTHREADS 512

__global__ __launch_bounds__(NTHREADS, 1) void vlad_fused_kernel(
    const float* __restrict__ x,       // [N,C,S]
    const float* __restrict__ conv_w,  // [K,C]
    const float* __restrict__ cent,    // [K,C]
    const float* __restrict__ aw,      // [C]
    const float* __restrict__ ab,      // [1]
    float* __restrict__ out)           // [N, K*C]
{
    __shared__ float s_conv[K_][132];   // padded: bank = (4k + c) % 32
    __shared__ float s_x[C_][66];       // padded: bank = (2c + s) % 32
    __shared__ float s_t[TS][66];       // d / u, transposed [s][k]
    __shared__ float s_aw[C_];
    __shared__ float s_alpha[TS];
    __shared__ float s_hmp[TS];
    __shared__ float s_wred[8][64];
    __shared__ float s_wsum[K_];
    __shared__ float s_vl[K_][130];
    __shared__ float s_rs[K_];
    __shared__ float s_fin;

    const int tid = threadIdx.x;
    const int n = blockIdx.x;
    const float bias = ab[0];

    // ---- load conv_w (K*C = 8192) and aw into LDS ----
    for (int i = tid; i < K_ * C_; i += NTHREADS)
        s_conv[i >> 7][i & 127] = conv_w[i];
    if (tid < C_) s_aw[tid] = aw[tid];

    // vlad accumulator mapping: k = kg + 16*jk, c = cg + 32*jc
    const int cg = tid & 31;
    const int kg = tid >> 5;            // 0..15
    float acc[4][4] = {};               // [jk][jc]

    // d-compute mapping: s = 4*sg + i, k = kq and kq+32
    const int sg = tid & 15;
    const int kq = tid >> 4;            // 0..31

    // softmax mapping: column ss, k-range q*8..q*8+7
    const int ss = tid >> 3;            // 0..63
    const int q  = tid & 7;
    float wpart[8] = {};

    const float* xn = x + (size_t)n * C_ * S_;

    __syncthreads();

    for (int t = 0; t < NTILE; ++t) {
        const int s0t = t * TS;

        // ---- stage x tile [C][TS] (zero-pad tail) ----
        for (int w = 0; w < 16; ++w) {
            int idx = tid + w * NTHREADS;       // 0..8191
            int c = idx >> 6, s = idx & 63;
            int gs = s0t + s;
            s_x[c][s] = (gs < S_) ? xn[c * S_ + gs] : 0.0f;
        }
        __syncthreads();

        // ---- alpha / hmp for column ss (8 threads per s, 16 c each) ----
        {
            float ssq = 0.f, hd = 0.f;
            #pragma unroll
            for (int i = 0; i < 16; ++i) {
                float v = s_x[q * 16 + i][ss];
                ssq += v * v;
                hd  += fmaxf(v, 0.f) * s_aw[q * 16 + i];
            }
            #pragma unroll
            for (int m = 1; m < 8; m <<= 1) {
                ssq += __shfl_xor(ssq, m);
                hd  += __shfl_xor(hd, m);
            }
            if (q == 0) {
                float norm = sqrtf(ssq);
                float hmp = fmaxf(hd + bias, 0.f);
                s_alpha[ss] = hmp / fmaxf(norm, 1e-12f);
                s_hmp[ss]   = hmp;
            }
        }

        // ---- d[k][s] = conv_w . x  (raw dot, no alpha yet) ----
        {
            float d0[4] = {}, d1[4] = {};
            #pragma unroll 4
            for (int c = 0; c < C_; ++c) {
                float a0 = s_conv[kq][c];
                float a1 = s_conv[kq + 32][c];
                #pragma unroll
                for (int i = 0; i < 4; ++i) {
                    float xv = s_x[c][4 * sg + i];
                    d0[i] += a0 * xv;
                    d1[i] += a1 * xv;
                }
            }
            #pragma unroll
            for (int i = 0; i < 4; ++i) {
                s_t[4 * sg + i][kq]      = d0[i];
                s_t[4 * sg + i][kq + 32] = d1[i];
            }
        }
        __syncthreads();

        // ---- softmax over k for column ss; write u into s_t in place ----
        {
            float alpha = s_alpha[ss], hmp = s_hmp[ss];
            float dv[8];
            #pragma unroll
            for (int i = 0; i < 8; ++i) dv[i] = s_t[ss][q * 8 + i] * alpha;
            float mx = dv[0];
            #pragma unroll
            for (int i = 1; i < 8; ++i) mx = fmaxf(mx, dv[i]);
            #pragma unroll
            for (int m = 1; m < 8; m <<= 1) mx = fmaxf(mx, __shfl_xor(mx, m));
            float sum = 0.f;
            #pragma unroll
            for (int i = 0; i < 8; ++i) { dv[i] = __expf(dv[i] - mx); sum += dv[i]; }
            #pragma unroll
            for (int m = 1; m < 8; m <<= 1) sum += __shfl_xor(sum, m);
            float inv = 1.0f / sum;
            float wl = hmp * inv;           // -> w = sa_unnorm * wl
            float ul = hmp * alpha * inv;   // -> u = sa_unnorm * ul
            #pragma unroll
            for (int i = 0; i < 8; ++i) {
                wpart[i] += dv[i] * wl;
                s_t[ss][q * 8 + i] = dv[i] * ul;
            }
        }
        __syncthreads();

        // ---- vlad accumulate: acc[jk][jc] += sum_s u[k][s] * x[c][s] ----
        for (int sb = 0; sb < TS; sb += 4) {
            float uv[4][4];
            #pragma unroll
            for (int jk = 0; jk < 4; ++jk)
                #pragma unroll
                for (int i = 0; i < 4; ++i)
                    uv[jk][i] = s_t[sb + i][kg + 16 * jk];
            #pragma unroll
            for (int jc = 0; jc < 4; ++jc) {
                int c = cg + 32 * jc;
                float xv[4];
                #pragma unroll
                for (int i = 0; i < 4; ++i) xv[i] = s_x[c][sb + i];
                #pragma unroll
                for (int jk = 0; jk < 4; ++jk)
                    #pragma unroll
                    for (int i = 0; i < 4; ++i)
                        acc[jk][jc] += uv[jk][i] * xv[i];
            }
        }
        __syncthreads();
    }

    // ---- reduce Wsum[k] = sum_s w ----
    {
        #pragma unroll
        for (int i = 0; i < 8; ++i) {
            float v = wpart[i];
            v += __shfl_xor(v, 8);
            v += __shfl_xor(v, 16);
            v += __shfl_xor(v, 32);
            wpart[i] = v;
        }
        int lane = tid & 63, wave = tid >> 6;
        if (lane < 8) {  // lane == q for ss = wave*8 + 0
            #pragma unroll
            for (int i = 0; i < 8; ++i)
                s_wred[wave][lane * 8 + i] = wpart[i];
        }
    }
    __syncthreads();
    if (tid < K_) {
        float v = 0.f;
        #pragma unroll
        for (int w = 0; w < 8; ++w) v += s_wred[w][tid];
        s_wsum[tid] = v;
    }
    __syncthreads();

    // ---- vlad -> LDS with centroid subtraction ----
    #pragma unroll
    for (int jk = 0; jk < 4; ++jk) {
        int k = kg + 16 * jk;
        float wk = s_wsum[k];
        #pragma unroll
        for (int jc = 0; jc < 4; ++jc) {
            int c = cg + 32 * jc;
            s_vl[k][c] = acc[jk][jc] - cent[k * C_ + c] * wk;
        }
    }
    __syncthreads();

    // ---- per-(k) row norm over c; stash normalized row sumsq in s_wred[0] ----
    {
        int k = tid >> 3;       // 0..63
        float ssq = 0.f;
        #pragma unroll
        for (int i = 0; i < 16; ++i) {
            float v = s_vl[k][q * 16 + i];
            ssq += v * v;
        }
        #pragma unroll
        for (int m = 1; m < 8; m <<= 1) ssq += __shfl_xor(ssq, m);
        if (q == 0) {
            float rs = 1.0f / fmaxf(sqrtf(ssq), 1e-12f);
            s_rs[k] = rs;
            s_wred[0][k] = ssq * rs * rs;
        }
    }
    __syncthreads();

    // ---- flat norm (applied twice, second analytically) ----
    if (tid < 64) {
        float v = s_wred[0][tid];
        #pragma unroll
        for (int m = 1; m < 64; m <<= 1) v += __shfl_xor(v, m);
        if (tid == 0) {
            float n1 = sqrtf(v);
            float sc1 = 1.0f / fmaxf(n1, 1e-12f);
            float n2 = n1 * sc1;
            float sc2 = 1.0f / fmaxf(n2, 1e-12f);
            s_fin = sc1 * sc2;
        }
    }
    __syncthreads();

    // ---- write out ----
    {
        float fs = s_fin;
        float* on = out + (size_t)n * (K_ * C_);
        for (int w = 0; w < 16; ++w) {
            int idx = tid + w * NTHREADS;
            int k = idx >> 7, c = idx & 127;
            on[idx] = s_vl[k][c] * s_rs[k] * fs;
        }
    }
}

extern "C" void kernel_launch(void* const* d_in, const int* in_sizes, int n_in,
                              void* d_out, int out_size, void* d_ws, size_t ws_size,
                              hipStream_t stream) {
    const float* x      = (const float*)d_in[0];
    const float* conv_w = (const float*)d_in[1];
    const float* cent   = (const float*)d_in[2];
    const float* aw     = (const float*)d_in[3];
    const float* ab     = (const float*)d_in[4];
    float* outp = (float*)d_out;

    vlad_fused_kernel<<<N_, NTHREADS, 0, stream>>>(x, conv_w, cent, aw, ab, outp);
}

// Round 2
// 116.083 us; speedup vs baseline: 2.1019x; 2.1019x over previous
//
#include <hip/hip_runtime.h>
#include <hip/hip_bf16.h>

#define N_ 256
#define C_ 128
#define S_ 961
#define K_ 64
#define TS 64
#define NTILE 16
#define NTHREADS 512

typedef __attribute__((ext_vector_type(4))) float f32x4;
typedef __attribute__((ext_vector_type(8))) short bf16x8;
typedef __attribute__((ext_vector_type(4))) unsigned short us4;

#define MFMA16(a, b, c) __builtin_amdgcn_mfma_f32_16x16x32_bf16((a), (b), (c), 0, 0, 0)

static __device__ __forceinline__ unsigned short f2bf(float f) {
    unsigned int u = __builtin_bit_cast(unsigned int, f);
    u += 0x7fffu + ((u >> 16) & 1u);
    return (unsigned short)(u >> 16);
}
static __device__ __forceinline__ float bf2f(unsigned short h) {
    unsigned int u = ((unsigned int)h) << 16;
    return __builtin_bit_cast(float, u);
}

__global__ __launch_bounds__(NTHREADS, 1) void vlad_mfma_kernel(
    const float* __restrict__ x,       // [N,C,S]
    const float* __restrict__ conv_w,  // [K,C]
    const float* __restrict__ cent,    // [K,C]
    const float* __restrict__ aw,      // [C]
    const float* __restrict__ ab,      // [1]
    float* __restrict__ out)           // [N, K*C]
{
    // xs: c-major (rows = c, 72-short pitch = 144B, 16B-aligned). Reused as vl in epilogue.
    __shared__ union {
        struct { unsigned short hi[C_][72]; unsigned short lo[C_][72]; } xs;
        float vl[K_][130];
    } sxv;
    __shared__ unsigned short s_xT_hi[TS][136];  // s-major (rows = s, 272B pitch)
    __shared__ unsigned short s_xT_lo[TS][136];
    __shared__ float s_d[K_][66];                // raw logits
    __shared__ unsigned short s_u_hi[K_][72];    // u = softmax*hmp*alpha, bf16 split
    __shared__ unsigned short s_u_lo[K_][72];
    __shared__ float s_alpha[TS], s_hmp[TS];
    __shared__ float s_ared_ssq[8][TS], s_ared_hd[8][TS];
    __shared__ float s_wred[8][K_];
    __shared__ float s_wsum[K_], s_rs[K_];
    __shared__ float s_fin;

    const int tid = threadIdx.x;
    const int n = blockIdx.x;
    const int lane = tid & 63;
    const int w = tid >> 6;          // wave 0..7
    const int la = lane & 15;
    const int lg = lane >> 4;
    const float bias = ab[0];
    const float* xn = x + (size_t)n * (C_ * S_);

    // staging mapping: 4c x 4s micro-block per thread
    const int cb = tid >> 4;         // 0..31
    const int c0 = cb * 4;
    const int s0l = (tid & 15) * 4;

    float awr[4];
    #pragma unroll
    for (int r = 0; r < 4; ++r) awr[r] = aw[c0 + r];

    // ---- GEMM1 wave assignment: n-tile nt1, m-tiles {mtb, mtb+1} ----
    const int nt1 = w & 3;
    const int mtb = (w >> 2) * 2;
    // preload conv_w A-fragments (hi/lo) into registers
    bf16x8 cwhi[2][4], cwlo[2][4];
    #pragma unroll
    for (int m2 = 0; m2 < 2; ++m2) {
        int row = la + 16 * (mtb + m2);
        #pragma unroll
        for (int cc = 0; cc < 4; ++cc) {
            const float* p = conv_w + row * C_ + 8 * lg + 32 * cc;
            #pragma unroll
            for (int i = 0; i < 8; ++i) {
                float v = p[i];
                unsigned short h = f2bf(v);
                cwhi[m2][cc][i] = (short)h;
                cwlo[m2][cc][i] = (short)f2bf(v - bf2f(h));
            }
        }
    }

    // ---- GEMM2 wave assignment: m-tile mt2 (k), c-tiles ctb4..ctb4+3 ----
    const int mt2 = w & 3;
    const int ctb4 = (w >> 2) * 4;
    f32x4 acc2[4];
    #pragma unroll
    for (int ct = 0; ct < 4; ++ct) acc2[ct] = (f32x4){0.f, 0.f, 0.f, 0.f};

    float wpart = 0.f;
    float px[4][4];

    // prefetch tile 0 (always in range: s0l+3 <= 63 < 961)
    {
        #pragma unroll
        for (int r = 0; r < 4; ++r) {
            const float* pr = xn + (size_t)(c0 + r) * S_ + s0l;
            px[r][0] = pr[0]; px[r][1] = pr[1]; px[r][2] = pr[2]; px[r][3] = pr[3];
        }
    }

    for (int t = 0; t < NTILE; ++t) {
        // ================= P0: convert + stage + alpha partials =================
        unsigned short hv[4][4], lv[4][4];
        float ssqp[4] = {0.f, 0.f, 0.f, 0.f};
        float hdp[4]  = {0.f, 0.f, 0.f, 0.f};
        #pragma unroll
        for (int r = 0; r < 4; ++r) {
            #pragma unroll
            for (int j = 0; j < 4; ++j) {
                float f = px[r][j];
                unsigned short h = f2bf(f);
                unsigned short l = f2bf(f - bf2f(h));
                hv[r][j] = h; lv[r][j] = l;
                ssqp[j] += f * f;
                hdp[j]  += fmaxf(f, 0.f) * awr[r];
            }
        }
        #pragma unroll
        for (int r = 0; r < 4; ++r) {
            us4 a = {hv[r][0], hv[r][1], hv[r][2], hv[r][3]};
            us4 b = {lv[r][0], lv[r][1], lv[r][2], lv[r][3]};
            *(us4*)&sxv.xs.hi[c0 + r][s0l] = a;
            *(us4*)&sxv.xs.lo[c0 + r][s0l] = b;
        }
        #pragma unroll
        for (int j = 0; j < 4; ++j) {
            int srow = s0l + j;
            int cidx = (4 * cb) ^ ((((srow) >> 3) & 1) << 3);  // swizzled short-index
            us4 a = {hv[0][j], hv[1][j], hv[2][j], hv[3][j]};
            us4 b = {lv[0][j], lv[1][j], lv[2][j], lv[3][j]};
            *(us4*)&s_xT_hi[srow][cidx] = a;
            *(us4*)&s_xT_lo[srow][cidx] = b;
        }
        // reduce alpha partials over cb-within-wave (tid bits 4,5)
        #pragma unroll
        for (int j = 0; j < 4; ++j) {
            ssqp[j] += __shfl_xor(ssqp[j], 16);
            ssqp[j] += __shfl_xor(ssqp[j], 32);
            hdp[j]  += __shfl_xor(hdp[j], 16);
            hdp[j]  += __shfl_xor(hdp[j], 32);
        }
        if (((tid >> 4) & 3) == 0) {
            f32x4 a = {ssqp[0], ssqp[1], ssqp[2], ssqp[3]};
            f32x4 b = {hdp[0], hdp[1], hdp[2], hdp[3]};
            *(f32x4*)&s_ared_ssq[w][s0l] = a;
            *(f32x4*)&s_ared_hd[w][s0l]  = b;
        }
        __syncthreads();  // A

        // ================= P1: prefetch t+1 + GEMM1 + alpha finalize =================
        if (t + 1 < NTILE) {
            int gs = (t + 1) * TS + s0l;
            #pragma unroll
            for (int r = 0; r < 4; ++r) {
                const float* pr = xn + (size_t)(c0 + r) * S_ + gs;
                if (gs + 3 < S_) {
                    px[r][0] = pr[0]; px[r][1] = pr[1]; px[r][2] = pr[2]; px[r][3] = pr[3];
                } else {
                    #pragma unroll
                    for (int j = 0; j < 4; ++j)
                        px[r][j] = (gs + j < S_) ? pr[j] : 0.f;
                }
            }
        }
        {
            f32x4 d0 = {0.f, 0.f, 0.f, 0.f}, d1 = {0.f, 0.f, 0.f, 0.f};
            int srow = la + 16 * nt1;
            int swz = (((srow) >> 3) & 1) << 3;
            #pragma unroll
            for (int cc = 0; cc < 4; ++cc) {
                int cidx = (8 * lg + 32 * cc) ^ swz;
                bf16x8 bh = *(const bf16x8*)&s_xT_hi[srow][cidx];
                bf16x8 bl = *(const bf16x8*)&s_xT_lo[srow][cidx];
                d0 = MFMA16(cwlo[0][cc], bh, d0);
                d0 = MFMA16(cwhi[0][cc], bl, d0);
                d0 = MFMA16(cwhi[0][cc], bh, d0);
                d1 = MFMA16(cwlo[1][cc], bh, d1);
                d1 = MFMA16(cwhi[1][cc], bl, d1);
                d1 = MFMA16(cwhi[1][cc], bh, d1);
            }
            #pragma unroll
            for (int i = 0; i < 4; ++i) {
                s_d[16 * mtb + 4 * lg + i][16 * nt1 + la]       = d0[i];
                s_d[16 * (mtb + 1) + 4 * lg + i][16 * nt1 + la] = d1[i];
            }
        }
        if (tid < TS) {
            float ssq = 0.f, hd = 0.f;
            #pragma unroll
            for (int q = 0; q < 8; ++q) {
                ssq += s_ared_ssq[q][tid];
                hd  += s_ared_hd[q][tid];
            }
            bool valid = (t * TS + tid) < S_;
            float hmp = valid ? fmaxf(hd + bias, 0.f) : 0.f;
            s_hmp[tid] = hmp;
            s_alpha[tid] = hmp / fmaxf(sqrtf(ssq), 1e-12f);
        }
        __syncthreads();  // B

        // ================= P2: softmax (wave w owns s = 8w..8w+7, lane = k) =================
        {
            float uu[8];
            #pragma unroll
            for (int j = 0; j < 8; ++j) {
                int s = 8 * w + j;
                float d = s_d[lane][s];
                float al = s_alpha[s], hm = s_hmp[s];
                float dv = d * al;
                float mx = dv;
                #pragma unroll
                for (int m = 1; m < 64; m <<= 1) mx = fmaxf(mx, __shfl_xor(mx, m));
                float p = __expf(dv - mx);
                float sm = p;
                #pragma unroll
                for (int m = 1; m < 64; m <<= 1) sm += __shfl_xor(sm, m);
                float wv = p * hm / sm;     // w[k][s]
                wpart += wv;
                uu[j] = wv * al;            // u[k][s]
            }
            bf16x8 h8, l8;
            #pragma unroll
            for (int j = 0; j < 8; ++j) {
                unsigned short h = f2bf(uu[j]);
                h8[j] = (short)h;
                l8[j] = (short)f2bf(uu[j] - bf2f(h));
            }
            *(bf16x8*)&s_u_hi[lane][8 * w] = h8;
            *(bf16x8*)&s_u_lo[lane][8 * w] = l8;
        }
        __syncthreads();  // C

        // ================= P3: GEMM2 accumulate =================
        {
            #pragma unroll
            for (int sc = 0; sc < 2; ++sc) {
                bf16x8 ah = *(const bf16x8*)&s_u_hi[la + 16 * mt2][8 * lg + 32 * sc];
                bf16x8 al8 = *(const bf16x8*)&s_u_lo[la + 16 * mt2][8 * lg + 32 * sc];
                #pragma unroll
                for (int ct = 0; ct < 4; ++ct) {
                    int c = la + 16 * (ctb4 + ct);
                    bf16x8 bh = *(const bf16x8*)&sxv.xs.hi[c][8 * lg + 32 * sc];
                    bf16x8 bl = *(const bf16x8*)&sxv.xs.lo[c][8 * lg + 32 * sc];
                    acc2[ct] = MFMA16(al8, bh, acc2[ct]);
                    acc2[ct] = MFMA16(ah, bl, acc2[ct]);
                    acc2[ct] = MFMA16(ah, bh, acc2[ct]);
                }
            }
        }
        __syncthreads();  // D
    }

    // ================= epilogue =================
    s_wred[w][lane] = wpart;
    __syncthreads();
    if (tid < K_) {
        float v = 0.f;
        #pragma unroll
        for (int q = 0; q < 8; ++q) v += s_wred[q][tid];
        s_wsum[tid] = v;
    }
    __syncthreads();

    // vlad -> LDS (union overwrites xs; GEMM2 reads done at last barrier)
    {
        #pragma unroll
        for (int ct = 0; ct < 4; ++ct) {
            int c = la + 16 * (ctb4 + ct);
            #pragma unroll
            for (int i = 0; i < 4; ++i) {
                int k = 16 * mt2 + 4 * lg + i;
                sxv.vl[k][c] = acc2[ct][i] - cent[k * C_ + c] * s_wsum[k];
            }
        }
    }
    __syncthreads();

    // per-cluster row norm over c
    {
        int k = tid >> 3;
        int q = tid & 7;
        float ssq = 0.f;
        #pragma unroll
        for (int i = 0; i < 16; ++i) {
            float v = sxv.vl[k][q * 16 + i];
            ssq += v * v;
        }
        #pragma unroll
        for (int m = 1; m < 8; m <<= 1) ssq += __shfl_xor(ssq, m);
        if (q == 0) {
            float rs = 1.0f / fmaxf(sqrtf(ssq), 1e-12f);
            s_rs[k] = rs;
            s_wred[0][k] = ssq * rs * rs;
        }
    }
    __syncthreads();

    // flat norm applied twice
    if (tid < 64) {
        float v = s_wred[0][tid];
        #pragma unroll
        for (int m = 1; m < 64; m <<= 1) v += __shfl_xor(v, m);
        if (tid == 0) {
            float n1 = sqrtf(v);
            float sc1 = 1.0f / fmaxf(n1, 1e-12f);
            float n2 = n1 * sc1;
            float sc2 = 1.0f / fmaxf(n2, 1e-12f);
            s_fin = sc1 * sc2;
        }
    }
    __syncthreads();

    {
        float fs = s_fin;
        float* on = out + (size_t)n * (K_ * C_);
        #pragma unroll
        for (int it = 0; it < 16; ++it) {
            int idx = tid + it * NTHREADS;
            int k = idx >> 7, c = idx & 127;
            on[idx] = sxv.vl[k][c] * s_rs[k] * fs;
        }
    }
}

extern "C" void kernel_launch(void* const* d_in, const int* in_sizes, int n_in,
                              void* d_out, int out_size, void* d_ws, size_t ws_size,
                              hipStream_t stream) {
    const float* x      = (const float*)d_in[0];
    const float* conv_w = (const float*)d_in[1];
    const float* cent   = (const float*)d_in[2];
    const float* aw     = (const float*)d_in[3];
    const float* ab     = (const float*)d_in[4];
    float* outp = (float*)d_out;

    vlad_mfma_kernel<<<N_, NTHREADS, 0, stream>>>(x, conv_w, cent, aw, ab, outp);
}

// Round 4
// 75.101 us; speedup vs baseline: 3.2488x; 1.5457x over previous
//
#include <hip/hip_runtime.h>
#include <hip/hip_bf16.h>

#define N_ 256
#define C_ 128
#define S_ 961
#define K_ 64
#define TS 64
#define NTILE 16
#define NTHREADS 512

typedef __attribute__((ext_vector_type(4))) float f32x4;
typedef __attribute__((ext_vector_type(8))) short bf16x8;
typedef __attribute__((ext_vector_type(4))) unsigned short us4;

#define MFMA16(a, b, c) __builtin_amdgcn_mfma_f32_16x16x32_bf16((a), (b), (c), 0, 0, 0)

// split f into hi (round-half-up) + lo (trunc); pair error <= 2^-17 |f|
static __device__ __forceinline__ void split_bf(float f, unsigned short& h, unsigned short& l) {
    unsigned int u = __builtin_bit_cast(unsigned int, f);
    unsigned int ur = (u + 0x8000u) & 0xFFFF0000u;
    h = (unsigned short)(ur >> 16);
    float r = f - __builtin_bit_cast(float, ur);
    l = (unsigned short)(__builtin_bit_cast(unsigned int, r) >> 16);
}

template <int CTRL>
static __device__ __forceinline__ float dpp_add(float v) {
    int sw = __builtin_amdgcn_update_dpp(0, __builtin_bit_cast(int, v), CTRL, 0xF, 0xF, true);
    return v + __builtin_bit_cast(float, sw);
}
// sum over all 64 lanes, result broadcast to every lane (4 VALU-DPP + 2 shfl)
static __device__ __forceinline__ float wave_sum64(float v) {
    v = dpp_add<0xB1>(v);    // quad_perm [1,0,3,2]  (xor 1)
    v = dpp_add<0x4E>(v);    // quad_perm [2,3,0,1]  (xor 2)
    v = dpp_add<0x141>(v);   // row_half_mirror      (xor 4-equiv)
    v = dpp_add<0x140>(v);   // row_mirror           (xor 8-equiv)
    v += __shfl_xor(v, 16);
    v += __shfl_xor(v, 32);
    return v;
}

__global__ __launch_bounds__(NTHREADS, 1) void vlad_mfma_kernel(
    const float* __restrict__ x,       // [N,C,S]
    const float* __restrict__ conv_w,  // [K,C]
    const float* __restrict__ cent,    // [K,C]
    const float* __restrict__ aw,      // [C]
    const float* __restrict__ ab,      // [1]
    float* __restrict__ out)           // [N, K*C]
{
    __shared__ union {
        struct { unsigned short hi[C_][72]; unsigned short lo[C_][72]; } xs;  // c-major
        float vl[K_][130];
    } sxv;
    __shared__ unsigned short s_xT_hi[TS][136];  // s-major, swizzled
    __shared__ unsigned short s_xT_lo[TS][136];
    __shared__ float s_d[K_][68];                // raw logits (pitch 68: b128 rows, 2-way writes)
    __shared__ unsigned short s_u_hi[K_][72];
    __shared__ unsigned short s_u_lo[K_][72];
    __shared__ float s_alpha[TS], s_hmp[TS];
    __shared__ float s_ared_ssq[8][TS], s_ared_hd[8][TS];
    __shared__ float s_wred[8][K_];
    __shared__ float s_wsum[K_], s_rs[K_];
    __shared__ float s_fin;

    const int tid = threadIdx.x;
    const int n = blockIdx.x;
    const int lane = tid & 63;
    const int w = tid >> 6;          // wave 0..7
    const int la = lane & 15;
    const int lg = lane >> 4;
    const float bias = ab[0];
    const float* xn = x + (size_t)n * (C_ * S_);

    // staging mapping: 4c x 4s micro-block per thread
    const int cb = tid >> 4;         // 0..31
    const int c0 = cb * 4;
    const int s0l = (tid & 15) * 4;

    float awr[4];
    #pragma unroll
    for (int r = 0; r < 4; ++r) awr[r] = aw[c0 + r];

    // ---- GEMM1 wave assignment: n-tile nt1, m-tiles {mtb, mtb+1} ----
    const int nt1 = w & 3;
    const int mtb = (w >> 2) * 2;
    bf16x8 cwhi[2][4], cwlo[2][4];
    #pragma unroll
    for (int m2 = 0; m2 < 2; ++m2) {
        int row = la + 16 * (mtb + m2);
        #pragma unroll
        for (int cc = 0; cc < 4; ++cc) {
            const float* p = conv_w + row * C_ + 8 * lg + 32 * cc;
            #pragma unroll
            for (int i = 0; i < 8; ++i) {
                unsigned short h, l;
                split_bf(p[i], h, l);
                cwhi[m2][cc][i] = (short)h;
                cwlo[m2][cc][i] = (short)l;
            }
        }
    }

    // ---- GEMM2 wave assignment: 2 m-tiles x 2 c-tiles per wave ----
    const int mtb2 = (w & 1) * 2;        // mt in {mtb2, mtb2+1}
    const int ctb2 = (w >> 1) * 2;       // ct in {ctb2, ctb2+1}
    f32x4 acc2[2][2];
    #pragma unroll
    for (int m = 0; m < 2; ++m)
        #pragma unroll
        for (int ci = 0; ci < 2; ++ci) acc2[m][ci] = (f32x4){0.f, 0.f, 0.f, 0.f};

    float wpart = 0.f;
    float px[4][4];

    // prefetch tile 0
    #pragma unroll
    for (int r = 0; r < 4; ++r) {
        const float* pr = xn + (size_t)(c0 + r) * S_ + s0l;
        px[r][0] = pr[0]; px[r][1] = pr[1]; px[r][2] = pr[2]; px[r][3] = pr[3];
    }

    __syncthreads();

    for (int t = 0; t < NTILE; ++t) {
        // ================= P0: convert + stage + alpha partials =================
        unsigned short hv[4][4], lv[4][4];
        float ssqp[4] = {0.f, 0.f, 0.f, 0.f};
        float hdp[4]  = {0.f, 0.f, 0.f, 0.f};
        #pragma unroll
        for (int r = 0; r < 4; ++r) {
            #pragma unroll
            for (int j = 0; j < 4; ++j) {
                float f = px[r][j];
                split_bf(f, hv[r][j], lv[r][j]);
                ssqp[j] += f * f;
                hdp[j]  += fmaxf(f, 0.f) * awr[r];
            }
        }
        #pragma unroll
        for (int r = 0; r < 4; ++r) {
            us4 a = {hv[r][0], hv[r][1], hv[r][2], hv[r][3]};
            us4 b = {lv[r][0], lv[r][1], lv[r][2], lv[r][3]};
            *(us4*)&sxv.xs.hi[c0 + r][s0l] = a;
            *(us4*)&sxv.xs.lo[c0 + r][s0l] = b;
        }
        #pragma unroll
        for (int j = 0; j < 4; ++j) {
            int srow = s0l + j;
            int cidx = (4 * cb) ^ (((srow >> 3) & 3) << 3);
            us4 a = {hv[0][j], hv[1][j], hv[2][j], hv[3][j]};
            us4 b = {lv[0][j], lv[1][j], lv[2][j], lv[3][j]};
            *(us4*)&s_xT_hi[srow][cidx] = a;
            *(us4*)&s_xT_lo[srow][cidx] = b;
        }
        #pragma unroll
        for (int j = 0; j < 4; ++j) {
            ssqp[j] += __shfl_xor(ssqp[j], 16);
            ssqp[j] += __shfl_xor(ssqp[j], 32);
            hdp[j]  += __shfl_xor(hdp[j], 16);
            hdp[j]  += __shfl_xor(hdp[j], 32);
        }
        if (((tid >> 4) & 3) == 0) {
            f32x4 a = {ssqp[0], ssqp[1], ssqp[2], ssqp[3]};
            f32x4 b = {hdp[0], hdp[1], hdp[2], hdp[3]};
            *(f32x4*)&s_ared_ssq[w][s0l] = a;
            *(f32x4*)&s_ared_hd[w][s0l]  = b;
        }
        __syncthreads();  // A

        // ================= P1: prefetch t+1 + GEMM1 + alpha finalize =================
        if (t + 1 < NTILE) {
            int gs = (t + 1) * TS + s0l;
            #pragma unroll
            for (int r = 0; r < 4; ++r) {
                const float* pr = xn + (size_t)(c0 + r) * S_ + gs;
                if (gs + 3 < S_) {
                    px[r][0] = pr[0]; px[r][1] = pr[1]; px[r][2] = pr[2]; px[r][3] = pr[3];
                } else {
                    #pragma unroll
                    for (int j = 0; j < 4; ++j)
                        px[r][j] = (gs + j < S_) ? pr[j] : 0.f;
                }
            }
        }
        {
            f32x4 d0 = {0.f, 0.f, 0.f, 0.f}, d1 = {0.f, 0.f, 0.f, 0.f};
            int srow = la + 16 * nt1;
            int swz = ((srow >> 3) & 3) << 3;
            #pragma unroll
            for (int cc = 0; cc < 4; ++cc) {
                int cidx = (8 * lg + 32 * cc) ^ swz;
                bf16x8 bh = *(const bf16x8*)&s_xT_hi[srow][cidx];
                bf16x8 bl = *(const bf16x8*)&s_xT_lo[srow][cidx];
                d0 = MFMA16(cwlo[0][cc], bh, d0);
                d0 = MFMA16(cwhi[0][cc], bl, d0);
                d0 = MFMA16(cwhi[0][cc], bh, d0);
                d1 = MFMA16(cwlo[1][cc], bh, d1);
                d1 = MFMA16(cwhi[1][cc], bl, d1);
                d1 = MFMA16(cwhi[1][cc], bh, d1);
            }
            #pragma unroll
            for (int i = 0; i < 4; ++i) {
                s_d[16 * mtb + 4 * lg + i][16 * nt1 + la]       = d0[i];
                s_d[16 * (mtb + 1) + 4 * lg + i][16 * nt1 + la] = d1[i];
            }
        }
        if (tid < TS) {
            float ssq = 0.f, hd = 0.f;
            #pragma unroll
            for (int q = 0; q < 8; ++q) {
                ssq += s_ared_ssq[q][tid];
                hd  += s_ared_hd[q][tid];
            }
            bool valid = (t * TS + tid) < S_;
            float hmp = valid ? fmaxf(hd + bias, 0.f) : 0.f;
            s_hmp[tid] = hmp;
            s_alpha[tid] = hmp / fmaxf(sqrtf(ssq), 1e-12f);
        }
        __syncthreads();  // B

        // ================= P2: softmax, no max-subtract, DPP reduction =================
        {
            const float* drow = &s_d[lane][8 * w];
            f32x4 dA = *(const f32x4*)drow;
            f32x4 dB = *(const f32x4*)(drow + 4);
            float uu[8];
            #pragma unroll
            for (int j = 0; j < 8; ++j) {
                int s = 8 * w + j;
                float al = s_alpha[s], hm = s_hmp[s];
                float dv = ((j < 4) ? dA[j] : dB[j - 4]) * al;
                float e = __expf(dv);
                float sm = wave_sum64(e);
                float wv = e * hm * __builtin_amdgcn_rcpf(sm);
                wpart += wv;
                uu[j] = wv * al;
            }
            bf16x8 h8, l8;
            #pragma unroll
            for (int j = 0; j < 8; ++j) {
                unsigned short hh, ll;
                split_bf(uu[j], hh, ll);
                h8[j] = (short)hh;
                l8[j] = (short)ll;
            }
            *(bf16x8*)&s_u_hi[lane][8 * w] = h8;
            *(bf16x8*)&s_u_lo[lane][8 * w] = l8;
        }
        __syncthreads();  // C

        // ================= P3: GEMM2 accumulate (2mt x 2ct per wave) =================
        {
            #pragma unroll
            for (int sc = 0; sc < 2; ++sc) {
                bf16x8 ah[2], al8[2];
                #pragma unroll
                for (int m = 0; m < 2; ++m) {
                    ah[m]  = *(const bf16x8*)&s_u_hi[la + 16 * (mtb2 + m)][8 * lg + 32 * sc];
                    al8[m] = *(const bf16x8*)&s_u_lo[la + 16 * (mtb2 + m)][8 * lg + 32 * sc];
                }
                #pragma unroll
                for (int ci = 0; ci < 2; ++ci) {
                    int c = la + 16 * (ctb2 + ci);
                    bf16x8 bh = *(const bf16x8*)&sxv.xs.hi[c][8 * lg + 32 * sc];
                    bf16x8 bl = *(const bf16x8*)&sxv.xs.lo[c][8 * lg + 32 * sc];
                    #pragma unroll
                    for (int m = 0; m < 2; ++m) {
                        acc2[m][ci] = MFMA16(al8[m], bh, acc2[m][ci]);
                        acc2[m][ci] = MFMA16(ah[m], bl, acc2[m][ci]);
                        acc2[m][ci] = MFMA16(ah[m], bh, acc2[m][ci]);
                    }
                }
            }
        }
        __syncthreads();  // D
    }

    // ================= epilogue =================
    s_wred[w][lane] = wpart;
    __syncthreads();
    if (tid < K_) {
        float v = 0.f;
        #pragma unroll
        for (int q = 0; q < 8; ++q) v += s_wred[q][tid];
        s_wsum[tid] = v;
    }
    __syncthreads();

    {
        #pragma unroll
        for (int m = 0; m < 2; ++m) {
            #pragma unroll
            for (int ci = 0; ci < 2; ++ci) {
                int c = la + 16 * (ctb2 + ci);
                #pragma unroll
                for (int i = 0; i < 4; ++i) {
                    int k = 16 * (mtb2 + m) + 4 * lg + i;
                    sxv.vl[k][c] = acc2[m][ci][i] - cent[k * C_ + c] * s_wsum[k];
                }
            }
        }
    }
    __syncthreads();

    // per-cluster row norm over c
    {
        int k = tid >> 3;
        int q = tid & 7;
        float ssq = 0.f;
        #pragma unroll
        for (int i = 0; i < 16; ++i) {
            float v = sxv.vl[k][q * 16 + i];
            ssq += v * v;
        }
        #pragma unroll
        for (int m = 1; m < 8; m <<= 1) ssq += __shfl_xor(ssq, m);
        if (q == 0) {
            float rs = 1.0f / fmaxf(sqrtf(ssq), 1e-12f);
            s_rs[k] = rs;
            s_wred[0][k] = ssq * rs * rs;
        }
    }
    __syncthreads();

    if (tid < 64) {
        float v = s_wred[0][tid];
        #pragma unroll
        for (int m = 1; m < 64; m <<= 1) v += __shfl_xor(v, m);
        if (tid == 0) {
            float n1 = sqrtf(v);
            float sc1 = 1.0f / fmaxf(n1, 1e-12f);
            float n2 = n1 * sc1;
            float sc2 = 1.0f / fmaxf(n2, 1e-12f);
            s_fin = sc1 * sc2;
        }
    }
    __syncthreads();

    {
        float fs = s_fin;
        float* on = out + (size_t)n * (K_ * C_);
        #pragma unroll
        for (int it = 0; it < 16; ++it) {
            int idx = tid + it * NTHREADS;
            int k = idx >> 7, c = idx & 127;
            on[idx] = sxv.vl[k][c] * s_rs[k] * fs;
        }
    }
}

extern "C" void kernel_launch(void* const* d_in, const int* in_sizes, int n_in,
                              void* d_out, int out_size, void* d_ws, size_t ws_size,
                              hipStream_t stream) {
    const float* x      = (const float*)d_in[0];
    const float* conv_w = (const float*)d_in[1];
    const float* cent   = (const float*)d_in[2];
    const float* aw     = (const float*)d_in[3];
    const float* ab     = (const float*)d_in[4];
    float* outp = (float*)d_out;

    vlad_mfma_kernel<<<N_, NTHREADS, 0, stream>>>(x, conv_w, cent, aw, ab, outp);
}